// Round 15
// baseline (343.900 us; speedup 1.0000x reference)
//
#include <hip/hip_runtime.h>

#define DEV __device__ __forceinline__

typedef __bf16 bf16x8 __attribute__((ext_vector_type(8)));
typedef float f32x4 __attribute__((ext_vector_type(4)));

DEV float bflo(unsigned int u) { union { unsigned int x; float f; } c; c.x = u << 16; return c.f; }
DEV unsigned short f2bf(float f) {
  union { float f; unsigned int u; } c; c.f = f;
  unsigned int u = c.u;
  return (unsigned short)((u + 0x7fffu + ((u >> 16) & 1u)) >> 16);
}
DEV unsigned int pkbf(float a, float b) {  // {lo=a, hi=b} bf16 pair, RNE
  unsigned int r;
  asm("v_cvt_pk_bf16_f32 %0, %1, %2" : "=v"(r) : "v"(a), "v"(b));
  return r;
}
DEV float gelu_fast(float y) {  // tanh-form GELU via exp2, ~7 VALU ops
  float y2 = y * y;
  float z = y * fmaf(y2, 0.10294348f, 2.30220842f);
  float e = __builtin_amdgcn_exp2f(z);
  float r = __builtin_amdgcn_rcpf(e + 1.0f);
  return fmaf(-y, r, y);
}

DEV void gload16(const void* g, void* l) {
  __builtin_amdgcn_global_load_lds((const __attribute__((address_space(1))) void*)g,
                                   (__attribute__((address_space(3))) void*)l, 16, 0, 0);
}

// ---------------- fused weight convert + zero-pad (dst regions contiguous) --------
__global__ __launch_bounds__(256) void wconv_all(const float* __restrict__ s0,
                                                 const float* __restrict__ s1,
                                                 const float* __restrict__ s2,
                                                 const float* __restrict__ s3,
                                                 unsigned short* __restrict__ dst) {
  int i = blockIdx.x * 256 + threadIdx.x;  // < 516096
  const float* src; int off, real;
  if (i < 122880)      { src = s0; off = i;          real = 110592; }
  else if (i < 172032) { src = s1; off = i - 122880; real = 36864; }
  else if (i < 319488) { src = s2; off = i - 172032; real = 147456; }
  else                 { src = s3; off = i - 319488; real = 147456; }
  dst[i] = (off < real) ? f2bf(src[off]) : (unsigned short)0;
}

// ---------------- bias+mask precompute: BMT4[wth][kk/4][q][kk%4], bf16, log2e ------
__global__ __launch_bounds__(256) void bmt_kernel(const float* __restrict__ rel_table,
                                                  unsigned short* __restrict__ bmt4) {
  int wth = blockIdx.x;            // 0..47 = wt*6 + h
  int wt = wth / 6, h = wth - wt * 6;
  int r = blockIdx.y;              // 0..87 : kk = 4r+i
  unsigned short* row = bmt4 + (((size_t)wth * 88 + r) * 352) * 4;
  for (int q = threadIdx.x; q < 352; q += 256) {
    int mb_q = 0, cls_q = 0;
    bool qv = q < 343;
    if (qv) {
      int ii_q = q / 49, rem_q = q - ii_q * 49;
      int jj_q = rem_q / 7, ww_q = rem_q - jj_q * 7;
      mb_q = ii_q * 169 + jj_q * 13 + ww_q;
      int cd_q = (wt & 4) ? (ii_q < 4 ? 1 : 2) : 0;
      int ch_q = (wt & 2) ? (jj_q < 4 ? 1 : 2) : 0;
      int cw_q = (wt & 1) ? (ww_q < 4 ? 1 : 2) : 0;
      cls_q = cd_q * 9 + ch_q * 3 + cw_q;
    }
    unsigned short ov[4];
#pragma unroll
    for (int i = 0; i < 4; i++) {
      int kk = 4 * r + i;
      float v;
      if (kk >= 343) v = -30000.f;
      else if (!qv) v = 0.f;
      else {
        int ii_k = kk / 49, rem_k = kk - ii_k * 49;
        int jj_k = rem_k / 7, ww_k = rem_k - jj_k * 7;
        int mb_k = ii_k * 169 + jj_k * 13 + ww_k;
        int cd_k = (wt & 4) ? (ii_k < 4 ? 1 : 2) : 0;
        int ch_k = (wt & 2) ? (jj_k < 4 ? 1 : 2) : 0;
        int cw_k = (wt & 1) ? (ww_k < 4 ? 1 : 2) : 0;
        int cls_k = cd_k * 9 + ch_k * 3 + cw_k;
        v = rel_table[(mb_q - mb_k + 1098) * 6 + h] * 1.4426950408889634f;
        if (cls_q != cls_k) v -= 144.26950408889634f;
      }
      ov[i] = f2bf(v);
    }
    unsigned int lo = (unsigned)ov[0] | ((unsigned)ov[1] << 16);
    unsigned int hi = (unsigned)ov[2] | ((unsigned)ov[3] << 16);
    *(uint2*)(row + q * 4) = make_uint2(lo, hi);
  }
}

// ---------------- LayerNorm1 + roll + window gather ----------------
__global__ __launch_bounds__(256) void ln_kernel(const float* __restrict__ x,
                                                 const float* __restrict__ g,
                                                 const float* __restrict__ b,
                                                 unsigned short* __restrict__ out) {
  int row = (blockIdx.x << 2) + (threadIdx.x >> 6);
  int lane = threadIdx.x & 63;
  int w_ = row / 343, n_ = row - w_ * 343;
  int bb = w_ >> 6, wrem = w_ & 63;
  int wd = wrem >> 4, wh = (wrem >> 2) & 3, ww = wrem & 3;
  int ii = n_ / 49, rem = n_ - ii * 49;
  int jj = rem / 7, kk = rem - jj * 7;
  int d = wd * 7 + ii + 3; if (d >= 28) d -= 28;
  int hh = wh * 7 + jj + 3; if (hh >= 28) hh -= 28;
  int wb = ww * 7 + kk + 3; if (wb >= 28) wb -= 28;
  const float* xr = x + ((size_t)bb * 21952 + (d * 28 + hh) * 28 + wb) * 192;
  float v0 = xr[lane], v1 = xr[lane + 64], v2 = xr[lane + 128];
  float s = v0 + v1 + v2;
  float sq = v0 * v0 + v1 * v1 + v2 * v2;
#pragma unroll
  for (int o = 32; o > 0; o >>= 1) {
    s += __shfl_xor(s, o, 64);
    sq += __shfl_xor(sq, o, 64);
  }
  float mean = s * (1.0f / 192.0f);
  float var = sq * (1.0f / 192.0f) - mean * mean;
  float rstd = rsqrtf(var + 1e-5f);
  unsigned short* orow = out + (size_t)row * 192;
  orow[lane]       = f2bf((v0 - mean) * rstd * g[lane] + b[lane]);
  orow[lane + 64]  = f2bf((v1 - mean) * rstd * g[lane + 64] + b[lane + 64]);
  orow[lane + 128] = f2bf((v2 - mean) * rstd * g[lane + 128] + b[lane + 128]);
}

// ---------------- QKV GEMM 128x128, BK=32 (16KB LDS/buf -> 4 blocks/CU) ----------
__global__ __launch_bounds__(256) void gemm_qkv(
    const unsigned short* __restrict__ A, const unsigned short* __restrict__ W,
    const float* __restrict__ bias,
    unsigned short* __restrict__ oq, unsigned short* __restrict__ okk,
    unsigned short* __restrict__ ov) {
  __shared__ __align__(16) unsigned short As[2][128 * 32];
  __shared__ __align__(16) unsigned short Bs[2][128 * 32];
  const int K = 192;
  // bijective XCD swizzle (nwg=3430, q8=428, r8=6)
  const int orig = blockIdx.x;
  const int xcd = orig & 7, off = orig >> 3;
  const int wgid = (xcd < 6 ? xcd * 429 : 2574 + (xcd - 6) * 428) + off;
  const int by = wgid / 5, bx = wgid - by * 5;
  const int bm = by << 7, bn = bx << 7;

  const int tid = threadIdx.x;
  const int lane = tid & 63;
  const int wv = tid >> 6;
  const int wr = wv >> 1, wc = wv & 1;
  const int l15 = lane & 15, l4 = lane >> 4;

  f32x4 acc[4][4];
#pragma unroll
  for (int a = 0; a < 4; a++)
#pragma unroll
    for (int b2 = 0; b2 < 4; b2++) acc[a][b2] = (f32x4){0.f, 0.f, 0.f, 0.f};

  auto stage = [&](int kt, int buf) {  // exactly 4 gload16 per thread
#pragma unroll
    for (int i = 0; i < 2; i++) {
      int o = (i << 12) + (tid << 4);   // byte offset in 8KB tile
      int r = o >> 6;                   // row 0..127
      int c = (o >> 4) & 3;             // 16B chunk 0..3
      int sc = (c ^ (r & 3)) << 3;      // swizzled source col (elems)
      gload16(A + (size_t)(bm + r) * K + kt * 32 + sc, &As[buf][o >> 1]);
      gload16(W + (size_t)(bn + r) * K + kt * 32 + sc, &Bs[buf][o >> 1]);
    }
  };

  stage(0, 0);
  int cur = 0;
  for (int kt = 0; kt < 6; ++kt) {
    if (kt < 5) {
      stage(kt + 1, cur ^ 1);
      asm volatile("s_waitcnt vmcnt(4)" ::: "memory");  // tile kt landed; kt+1 in flight
    } else {
      asm volatile("s_waitcnt vmcnt(0)" ::: "memory");
    }
    __builtin_amdgcn_s_barrier();
    __builtin_amdgcn_sched_barrier(0);
    {
      bf16x8 af[4], bfr[4];
#pragma unroll
      for (int fm = 0; fm < 4; fm++) {
        int r = (wr << 6) + (fm << 4) + l15;
        af[fm] = *(const bf16x8*)(&As[cur][(r << 5) + ((l4 ^ (r & 3)) << 3)]);
      }
#pragma unroll
      for (int fn = 0; fn < 4; fn++) {
        int r = (wc << 6) + (fn << 4) + l15;
        bfr[fn] = *(const bf16x8*)(&Bs[cur][(r << 5) + ((l4 ^ (r & 3)) << 3)]);
      }
#pragma unroll
      for (int fm = 0; fm < 4; fm++)
#pragma unroll
        for (int fn = 0; fn < 4; fn++)
          acc[fm][fn] = __builtin_amdgcn_mfma_f32_16x16x32_bf16(bfr[fn], af[fm], acc[fm][fn], 0, 0, 0);
    }
    if (kt < 5) {
      __builtin_amdgcn_sched_barrier(0);
      __builtin_amdgcn_s_barrier();
      cur ^= 1;
    }
  }

#pragma unroll
  for (int fm = 0; fm < 4; fm++) {
    int gr = bm + (wr << 6) + (fm << 4) + l15;
    int w_ = gr / 343, n_ = gr - w_ * 343;
#pragma unroll
    for (int fn = 0; fn < 4; fn++) {
      int gc0 = bn + (wc << 6) + (fn << 4) + (l4 << 2);
      if (gc0 < 576) {
        float4 bv = *(const float4*)(bias + gc0);
        float v0 = acc[fm][fn][0] + bv.x, v1 = acc[fm][fn][1] + bv.y;
        float v2 = acc[fm][fn][2] + bv.z, v3 = acc[fm][fn][3] + bv.w;
        int which = gc0 / 192;
        int cc3 = gc0 - which * 192;
        int hh2 = cc3 >> 5, dd0 = cc3 & 31;
        size_t offo = ((size_t)(w_ * 6 + hh2) * 343 + n_) * 32 + dd0;
        if (which == 0) {
          const float sc = 0.17677669529663687f * 1.4426950408889634f;
          *(uint2*)(oq + offo) = make_uint2(pkbf(v0 * sc, v1 * sc), pkbf(v2 * sc, v3 * sc));
        } else if (which == 1) {
          *(uint2*)(okk + offo) = make_uint2(pkbf(v0, v1), pkbf(v2, v3));
        } else {
          *(uint2*)(ov + offo) = make_uint2(pkbf(v0, v1), pkbf(v2, v3));
        }
      }
    }
  }
}

// ---------------- fused proj + LN2 + MLP, weights STREAMED through LDS ------------
// 64 rows/block, 256 threads. Phase 2: 12 chunks of 64 hidden; W1c (64x192) and
// W2c (192x64) staged per chunk via global_load_lds into a double-buffered pair
// (12 gload16/thread, pre-swizzled source, linear dest), counted vmcnt(12) so the
// next chunk's stage is in flight across this chunk's FC1+GELU+FC2. All weight
// MFMA operands are swizzled ds_read_b128 — no per-lane scattered global loads.
__global__ __launch_bounds__(256, 2) void proj_mlp(
    const unsigned short* __restrict__ A,    // attn-out, window order
    const unsigned short* __restrict__ Wp, const float* __restrict__ bp,
    const float* __restrict__ x,
    const float* __restrict__ g2, const float* __restrict__ b2,
    const unsigned short* __restrict__ W1, const float* __restrict__ b1,
    const unsigned short* __restrict__ W2, const float* __restrict__ b2b,
    float* __restrict__ out) {
  __shared__ __align__(16) char smem[132096];
  unsigned short* As = (unsigned short*)smem;            // 64x192 (24K): A -> xw2s
  unsigned short* Wb0 = (unsigned short*)(smem + 24576);  // buf0: W1c 24K + W2c 24K
  unsigned short* Wb1 = (unsigned short*)(smem + 73728);  // buf1
  unsigned short* Hs = (unsigned short*)(smem + 122880);  // 64x72 (9216B)
  float* red = (float*)(smem + 122880);                   // LN2 scratch (aliases Hs)

  const int tid = threadIdx.x, lane = tid & 63, wv = tid >> 6;
  const int l15 = lane & 15, l4 = lane >> 4;
  const int bm = blockIdx.x << 6;

  // token-order row base addresses (residual + final store)
  int orow[4];
#pragma unroll
  for (int fm = 0; fm < 4; fm++) {
    int gr = bm + (fm << 4) + l15;
    int w_ = gr / 343, n_ = gr - w_ * 343;
    int bb = w_ >> 6, wrem = w_ & 63;
    int wd = wrem >> 4, wh = (wrem >> 2) & 3, ww = wrem & 3;
    int ii = n_ / 49, rem = n_ - ii * 49;
    int jj = rem / 7, kk = rem - jj * 7;
    int d = wd * 7 + ii + 3; if (d >= 28) d -= 28;
    int hh = wh * 7 + jj + 3; if (hh >= 28) hh -= 28;
    int wb = ww * 7 + kk + 3; if (wb >= 28) wb -= 28;
    orow[fm] = ((bb * 21952 + (d * 28 + hh) * 28 + wb) * 192);
  }

  // stage A tile 64x192 once (6 gload16/thread; linear dest, swizzled source)
#pragma unroll
  for (int i = 0; i < 6; i++) {
    int idx = (i << 8) + tid;
    int r = idx / 24, c = idx - r * 24;
    gload16(A + (size_t)(bm + r) * 192 + ((c ^ (r & 7)) << 3), As + r * 192 + (c << 3));
  }
  asm volatile("s_waitcnt vmcnt(0)" ::: "memory");
  __builtin_amdgcn_s_barrier();

  // ---- phase 1: proj GEMM (K=192; Wp frags direct — small, one-shot) ----
  f32x4 acc[4][3];
#pragma unroll
  for (int a = 0; a < 4; a++)
#pragma unroll
    for (int b_ = 0; b_ < 3; b_++) acc[a][b_] = (f32x4){0.f, 0.f, 0.f, 0.f};
#pragma unroll
  for (int ks = 0; ks < 6; ks++) {
    bf16x8 af[4], wpf[3];
#pragma unroll
    for (int fm = 0; fm < 4; fm++) {
      int r = (fm << 4) + l15;
      int ch = (ks << 2) + l4;
      af[fm] = *(const bf16x8*)(As + r * 192 + ((ch ^ (r & 7)) << 3));
    }
#pragma unroll
    for (int fn = 0; fn < 3; fn++) {
      int rr = wv * 48 + (fn << 4) + l15;
      wpf[fn] = *(const bf16x8*)(Wp + (size_t)rr * 192 + (ks << 5) + (l4 << 3));
    }
#pragma unroll
    for (int fm = 0; fm < 4; fm++)
#pragma unroll
      for (int fn = 0; fn < 3; fn++)
        acc[fm][fn] = __builtin_amdgcn_mfma_f32_16x16x32_bf16(wpf[fn], af[fm], acc[fm][fn], 0, 0, 0);
  }

  // ---- epilogue 1: +bias + x residual, LN2 stats ----
  float ps[4], psq[4];
#pragma unroll
  for (int fm = 0; fm < 4; fm++) {
    float s = 0.f, sq = 0.f;
#pragma unroll
    for (int fn = 0; fn < 3; fn++) {
      int gc0 = wv * 48 + (fn << 4) + (l4 << 2);
      float4 bv = *(const float4*)(bp + gc0);
      float4 xv = *(const float4*)(x + (size_t)orow[fm] + gc0);
      acc[fm][fn][0] += bv.x + xv.x;
      acc[fm][fn][1] += bv.y + xv.y;
      acc[fm][fn][2] += bv.z + xv.z;
      acc[fm][fn][3] += bv.w + xv.w;
#pragma unroll
      for (int i = 0; i < 4; i++) {
        float v = acc[fm][fn][i];
        s += v; sq += v * v;
      }
    }
    ps[fm] = s; psq[fm] = sq;
  }
#pragma unroll
  for (int fm = 0; fm < 4; fm++) {
    ps[fm] += __shfl_xor(ps[fm], 16, 64);
    ps[fm] += __shfl_xor(ps[fm], 32, 64);
    psq[fm] += __shfl_xor(psq[fm], 16, 64);
    psq[fm] += __shfl_xor(psq[fm], 32, 64);
  }
  __syncthreads();  // all proj As reads done; red usable
  if (l4 == 0) {
#pragma unroll
    for (int fm = 0; fm < 4; fm++) {
      int tr = (fm << 4) + l15;
      red[tr * 8 + wv] = ps[fm];
      red[tr * 8 + 4 + wv] = psq[fm];
    }
  }
  __syncthreads();
  if (tid < 64) {
    float s = red[tid * 8] + red[tid * 8 + 1] + red[tid * 8 + 2] + red[tid * 8 + 3];
    float sq = red[tid * 8 + 4] + red[tid * 8 + 5] + red[tid * 8 + 6] + red[tid * 8 + 7];
    float mean = s * (1.0f / 192.0f);
    float var = sq * (1.0f / 192.0f) - mean * mean;
    red[tid * 8] = mean;
    red[tid * 8 + 1] = rsqrtf(var + 1e-5f);
  }
  __syncthreads();
  // xnew -> packed bf16 regs; xw2 = LN2(xnew) -> LDS (As area, swizzled)
  unsigned int xnb[4][3][2];
#pragma unroll
  for (int fm = 0; fm < 4; fm++) {
    int tr = (fm << 4) + l15;
    float mean = red[tr * 8], rstd = red[tr * 8 + 1];
#pragma unroll
    for (int fn = 0; fn < 3; fn++) {
      int gc0 = wv * 48 + (fn << 4) + (l4 << 2);
      float4 gv = *(const float4*)(g2 + gc0);
      float4 b2v = *(const float4*)(b2 + gc0);
      float v0 = acc[fm][fn][0], v1 = acc[fm][fn][1];
      float v2 = acc[fm][fn][2], v3 = acc[fm][fn][3];
      xnb[fm][fn][0] = pkbf(v0, v1);
      xnb[fm][fn][1] = pkbf(v2, v3);
      float y0 = (v0 - mean) * rstd * gv.x + b2v.x;
      float y1 = (v1 - mean) * rstd * gv.y + b2v.y;
      float y2 = (v2 - mean) * rstd * gv.z + b2v.z;
      float y3 = (v3 - mean) * rstd * gv.w + b2v.w;
      int ch = gc0 >> 3;
      *(uint2*)(As + tr * 192 + ((ch ^ (tr & 7)) << 3) + (gc0 & 7)) =
          make_uint2(pkbf(y0, y1), pkbf(y2, y3));
    }
  }
  __syncthreads();  // xw2s visible; red reads done -> Hs/Wb writable

  // ---- phase 2: 12 chunks of 64 hidden; weights streamed via gload_lds ----
  // stage(cc, buf): W1c rows cc*64..+63 (64x192) then W2c rows 0..191, cols cc*64..
  auto stageW = [&](int cc, unsigned short* Wb) {
#pragma unroll
    for (int i = 0; i < 6; i++) {          // W1c: idx over 1536 16B chunks
      int idx = (i << 8) + tid;
      int rr = idx / 24, c = idx - rr * 24;
      gload16(W1 + (size_t)(cc * 64 + rr) * 192 + ((c ^ (rr & 7)) << 3),
              Wb + rr * 192 + (c << 3));
    }
    unsigned short* W2b = Wb + 64 * 192;
#pragma unroll
    for (int i = 0; i < 6; i++) {          // W2c: idx over 1536 16B chunks
      int idx = (i << 8) + tid;
      int j = idx >> 3, c = idx & 7;
      gload16(W2 + (size_t)j * 768 + cc * 64 + ((c ^ (j & 7)) << 3),
              W2b + j * 64 + (c << 3));
    }
  };

  f32x4 acc2[4][3];
#pragma unroll
  for (int a = 0; a < 4; a++)
#pragma unroll
    for (int b_ = 0; b_ < 3; b_++) acc2[a][b_] = (f32x4){0.f, 0.f, 0.f, 0.f};

  stageW(0, Wb0);
  int cur = 0;
  for (int cc = 0; cc < 12; ++cc) {
    unsigned short* Wc = cur ? Wb1 : Wb0;
    unsigned short* W2c = Wc + 64 * 192;
    if (cc < 11) {
      stageW(cc + 1, cur ? Wb0 : Wb1);
      asm volatile("s_waitcnt vmcnt(12)" ::: "memory");  // chunk cc landed; cc+1 in flight
    } else {
      asm volatile("s_waitcnt vmcnt(0)" ::: "memory");
    }
    __builtin_amdgcn_s_barrier();   // W ready; prev chunk's Hs reads also done
    __builtin_amdgcn_sched_barrier(0);
    // FC1: H[token fm*16+l15][hidden wv*16 + 4*l4+i], K=192
    f32x4 acc1[4];
#pragma unroll
    for (int a = 0; a < 4; a++) acc1[a] = (f32x4){0.f, 0.f, 0.f, 0.f};
#pragma unroll
    for (int ks = 0; ks < 6; ks++) {
      bf16x8 af[4], w1f;
      {
        int hrl = (wv << 4) + l15;
        int ch = (ks << 2) + l4;
        w1f = *(const bf16x8*)(Wc + hrl * 192 + ((ch ^ (hrl & 7)) << 3));
      }
#pragma unroll
      for (int fm = 0; fm < 4; fm++) {
        int r = (fm << 4) + l15;
        int ch = (ks << 2) + l4;
        af[fm] = *(const bf16x8*)(As + r * 192 + ((ch ^ (r & 7)) << 3));
      }
#pragma unroll
      for (int fm = 0; fm < 4; fm++)
        acc1[fm] = __builtin_amdgcn_mfma_f32_16x16x32_bf16(w1f, af[fm], acc1[fm], 0, 0, 0);
    }
    // GELU -> Hs[token r][hidden col 0..63]
    {
      int hc = (wv << 4) + (l4 << 2);
      float4 bv = *(const float4*)(b1 + (cc << 6) + hc);
#pragma unroll
      for (int fm = 0; fm < 4; fm++) {
        int r = (fm << 4) + l15;
        float g0 = gelu_fast(acc1[fm][0] + bv.x);
        float g1 = gelu_fast(acc1[fm][1] + bv.y);
        float g2_ = gelu_fast(acc1[fm][2] + bv.z);
        float g3 = gelu_fast(acc1[fm][3] + bv.w);
        *(uint2*)(Hs + r * 72 + hc) = make_uint2(pkbf(g0, g1), pkbf(g2_, g3));
      }
    }
    __syncthreads();  // Hs write -> read
    // FC2: K=64 (2 ksteps); B = W2c from LDS (swizzled)
#pragma unroll
    for (int ks = 0; ks < 2; ks++) {
      bf16x8 hf[4], w2f[3];
#pragma unroll
      for (int fm = 0; fm < 4; fm++) {
        int r = (fm << 4) + l15;
        hf[fm] = *(const bf16x8*)(Hs + r * 72 + (ks << 5) + (l4 << 3));
      }
#pragma unroll
      for (int fn = 0; fn < 3; fn++) {
        int j = wv * 48 + (fn << 4) + l15;
        int ch = (ks << 2) + l4;
        w2f[fn] = *(const bf16x8*)(W2c + j * 64 + ((ch ^ (j & 7)) << 3));
      }
#pragma unroll
      for (int fm = 0; fm < 4; fm++)
#pragma unroll
        for (int fn = 0; fn < 3; fn++)
          acc2[fm][fn] = __builtin_amdgcn_mfma_f32_16x16x32_bf16(w2f[fn], hf[fm], acc2[fm][fn], 0, 0, 0);
    }
    __builtin_amdgcn_sched_barrier(0);
    __builtin_amdgcn_s_barrier();  // FC2 Hs/W reads done before next GELU/stage overwrite
    cur ^= 1;
  }

  // ---- final epilogue: + b2 + xnew -> f32 out (token order), float4 stores ----
#pragma unroll
  for (int fm = 0; fm < 4; fm++) {
#pragma unroll
    for (int fn = 0; fn < 3; fn++) {
      int gc0 = wv * 48 + (fn << 4) + (l4 << 2);
      float4 bv = *(const float4*)(b2b + gc0);
      float4 o;
      o.x = acc2[fm][fn][0] + bv.x + bflo(xnb[fm][fn][0] & 0xffffu);
      o.y = acc2[fm][fn][1] + bv.y + bflo(xnb[fm][fn][0] >> 16);
      o.z = acc2[fm][fn][2] + bv.z + bflo(xnb[fm][fn][1] & 0xffffu);
      o.w = acc2[fm][fn][3] + bv.w + bflo(xnb[fm][fn][1] >> 16);
      *(float4*)(out + (size_t)orow[fm] + gc0) = o;
    }
  }
}

// ---------------- MFMA attention: LDS K/V^T, grouped grid, packed bias ----------
__global__ __launch_bounds__(256) void attn_mfma(const unsigned short* __restrict__ q,
                                                 const unsigned short* __restrict__ k,
                                                 const unsigned short* __restrict__ v,
                                                 const unsigned short* __restrict__ bmt4,
                                                 unsigned short* __restrict__ out) {
  __shared__ __align__(16) unsigned short Ks[352 * 32];
  __shared__ __align__(16) unsigned short Vt[32 * 360];

  // decode blockIdx: h slow, then window-class groups (BMT slab L2 locality)
  const int blk = blockIdx.x;
  const int h_ = blk >> 8;
  const int idx = blk & 255;
  const int cums[8] = {0, 108, 144, 180, 192, 228, 240, 252};
  int c = (idx >= 108) + (idx >= 144) + (idx >= 180) + (idx >= 192) +
          (idx >= 228) + (idx >= 240) + (idx >= 252);
  int r0 = idx - cums[c];
  int sh = (c & 2) ? 1 : 3, sw = (c & 1) ? 1 : 3;
  int p = ((c & 4) ? 1 : 3) * sh * sw;
  int b = r0 / p, q2 = r0 - b * p;
  int wd, wh, ww;
  if (c & 4) wd = 3; else { wd = q2 / (sh * sw); q2 -= wd * sh * sw; }
  if (c & 2) wh = 3; else { wh = q2 / sw; q2 -= wh * sw; }
  ww = (c & 1) ? 3 : q2;
  const int w_ = b * 64 + wd * 16 + wh * 4 + ww;
  const int wt = c;
  const int blkqkv = w_ * 6 + h_;

  const int t = threadIdx.x, lane = t & 63, wv = t >> 6;
  const int l15 = lane & 15, l4 = lane >> 4;
  const unsigned short* Qb = q + (size_t)blkqkv * (343 * 32);
  const unsigned short* Kb = k + (size_t)blkqkv * (343 * 32);
  const unsigned short* Vb = v + (size_t)blkqkv * (343 * 32);
  const unsigned short* bm4 = bmt4 + ((size_t)(wt * 6 + h_) * 88) * 352 * 4;

  // stage K (rows 343..351 zeroed), chunk-XOR swizzle for 2-way reads
  for (int cc = t; cc < 1408; cc += 256) {
    int r = cc >> 2, ch = cc & 3;
    int swc = ch ^ ((r >> 1) & 3);
    uint4 val = make_uint4(0, 0, 0, 0);
    if (r < 343) val = *(const uint4*)(Kb + r * 32 + ch * 8);
    *(uint4*)(Ks + r * 32 + swc * 8) = val;
  }
  // stage V^T: Vt[d][n] = V[n][d]; pad n in [343,352) zeroed
#pragma unroll
  for (int ch = 0; ch < 4; ch++) {
    for (int n = t; n < 343; n += 256) {
      union { uint4 u4; unsigned short us[8]; } val;
      val.u4 = *(const uint4*)(Vb + n * 32 + ch * 8);
#pragma unroll
      for (int j = 0; j < 8; j++) Vt[(ch * 8 + j) * 360 + n] = val.us[j];
    }
  }
  for (int cc = t; cc < 288; cc += 256) {
    int d = cc / 9, n = 343 + (cc - d * 9);
    Vt[d * 360 + n] = 0;
  }
  __syncthreads();

  const int ksw = (l4 ^ ((l15 >> 1) & 3)) << 3;

  for (int tq = wv; tq < 22; tq += 4) {
    int qrow = tq * 16 + l15; if (qrow > 342) qrow = 342;
    bf16x8 qf = *(const bf16x8*)(Qb + qrow * 32 + l4 * 8);

    unsigned int u0[22], u1[22];
    float lsum = 0.f;
    __builtin_amdgcn_s_setprio(1);
#pragma unroll
    for (int kt = 0; kt < 22; kt++) {
      bf16x8 kf = *(const bf16x8*)(Ks + (kt * 16 + l15) * 32 + ksw);
      f32x4 s = __builtin_amdgcn_mfma_f32_16x16x32_bf16(kf, qf, (f32x4){0.f, 0.f, 0.f, 0.f}, 0, 0, 0);
      const unsigned short* bp = bm4 + ((size_t)((kt << 2) + l4) * 352 + (tq << 4) + l15) * 4;
      uint2 bv = *(const uint2*)bp;
      float p0 = __builtin_amdgcn_exp2f(s[0] + bflo(bv.x & 0xffffu));
      float p1 = __builtin_amdgcn_exp2f(s[1] + bflo(bv.x >> 16));
      float p2 = __builtin_amdgcn_exp2f(s[2] + bflo(bv.y & 0xffffu));
      float p3 = __builtin_amdgcn_exp2f(s[3] + bflo(bv.y >> 16));
      lsum += (p0 + p1) + (p2 + p3);
      asm("v_cvt_pk_bf16_f32 %0, %1, %2" : "=v"(u0[kt]) : "v"(p0), "v"(p1));
      asm("v_cvt_pk_bf16_f32 %0, %1, %2" : "=v"(u1[kt]) : "v"(p2), "v"(p3));
    }
    __builtin_amdgcn_s_setprio(0);
    lsum += __shfl_xor(lsum, 16, 64);
    lsum += __shfl_xor(lsum, 32, 64);
    float inv = 1.0f / lsum;  // per-lane q = l15

    // O^T = mfma(V^T, P): lane holds O[q = l15][d = 4*l4 .. +3] (+16 for oacc1)
    f32x4 oacc0 = (f32x4){0.f, 0.f, 0.f, 0.f};
    f32x4 oacc1 = (f32x4){0.f, 0.f, 0.f, 0.f};
    __builtin_amdgcn_s_setprio(1);
#pragma unroll
    for (int ck = 0; ck < 11; ck++) {
      unsigned int dw[4];
#pragma unroll
      for (int d = 0; d < 4; d++) {
        int src = l15 + 16 * ((d >> 1) + 2 * (l4 & 1));
        unsigned int x = __shfl((d & 1) ? u1[2 * ck] : u0[2 * ck], src, 64);
        unsigned int y = __shfl((d & 1) ? u1[2 * ck + 1] : u0[2 * ck + 1], src, 64);
        dw[d] = (l4 < 2) ? x : y;
      }
      union { unsigned int u[4]; bf16x8 v; } pc;
      pc.u[0] = dw[0]; pc.u[1] = dw[1]; pc.u[2] = dw[2]; pc.u[3] = dw[3];
      bf16x8 vf0 = *(const bf16x8*)(Vt + (size_t)l15 * 360 + ck * 32 + l4 * 8);
      bf16x8 vf1 = *(const bf16x8*)(Vt + (size_t)(16 + l15) * 360 + ck * 32 + l4 * 8);
      oacc0 = __builtin_amdgcn_mfma_f32_16x16x32_bf16(vf0, pc.v, oacc0, 0, 0, 0);
      oacc1 = __builtin_amdgcn_mfma_f32_16x16x32_bf16(vf1, pc.v, oacc1, 0, 0, 0);
    }
    __builtin_amdgcn_s_setprio(0);

    int qg = tq * 16 + l15;
    if (qg < 343) {
      unsigned short* orow = out + ((size_t)w_ * 343 + qg) * 192 + h_ * 32;
      *(uint2*)(orow + (l4 << 2)) =
          make_uint2(pkbf(oacc0[0] * inv, oacc0[1] * inv), pkbf(oacc0[2] * inv, oacc0[3] * inv));
      *(uint2*)(orow + 16 + (l4 << 2)) =
          make_uint2(pkbf(oacc1[0] * inv, oacc1[1] * inv), pkbf(oacc1[2] * inv, oacc1[3] * inv));
    }
  }
}

// ---------------- launcher ----------------
extern "C" void kernel_launch(void* const* d_in, const int* in_sizes, int n_in,
                              void* d_out, int out_size, void* d_ws, size_t ws_size,
                              hipStream_t stream) {
  const float* x      = (const float*)d_in[0];
  const float* n1g    = (const float*)d_in[1];
  const float* n1b    = (const float*)d_in[2];
  const float* qkv_w  = (const float*)d_in[3];
  const float* qkv_b  = (const float*)d_in[4];
  const float* proj_w = (const float*)d_in[5];
  const float* proj_b = (const float*)d_in[6];
  const float* rel_t  = (const float*)d_in[7];
  const float* n2g    = (const float*)d_in[8];
  const float* n2b    = (const float*)d_in[9];
  const float* fc1_w  = (const float*)d_in[10];
  const float* fc1_b  = (const float*)d_in[11];
  const float* fc2_w  = (const float*)d_in[12];
  const float* fc2_b  = (const float*)d_in[13];

  char* ws = (char*)d_ws;
  // layout (bytes):
  // 0         W (QKV|PROJ|FC1|FC2)   1032192
  // 1032192   XW    87808x192 bf16   (33718272)   [ln1-out -> attn-out]
  // 34750464  Q_    1536x343x32 bf16 (33718272)
  // 68468736  K_    1536x343x32 bf16 (33718272)
  // 102187008 V_    1536x343x32 bf16 (33718272)
  // 135925248 BMT4  48x88x352x4 bf16 (11894784)
  if (ws_size < 147820032ull) return;
  unsigned short* WQKV  = (unsigned short*)(ws);
  unsigned short* WPROJ = (unsigned short*)(ws + 245760);
  unsigned short* WFC1  = (unsigned short*)(ws + 344064);
  unsigned short* WFC2  = (unsigned short*)(ws + 638976);
  unsigned short* XW    = (unsigned short*)(ws + 1032192);
  unsigned short* Q_    = (unsigned short*)(ws + 34750464);
  unsigned short* K_    = (unsigned short*)(ws + 68468736);
  unsigned short* V_    = (unsigned short*)(ws + 102187008);
  unsigned short* BMT4  = (unsigned short*)(ws + 135925248);
  float* OUT = (float*)d_out;

  wconv_all<<<2016, 256, 0, stream>>>(qkv_w, proj_w, fc1_w, fc2_w, WQKV);

  bmt_kernel<<<dim3(48, 88), 256, 0, stream>>>(rel_t, BMT4);

  ln_kernel<<<21952, 256, 0, stream>>>(x, n1g, n1b, XW);

  gemm_qkv<<<3430, 256, 0, stream>>>(XW, WQKV, qkv_b, Q_, K_, V_);

  attn_mfma<<<1536, 256, 0, stream>>>(Q_, K_, V_, BMT4, XW);

  proj_mlp<<<1372, 256, 0, stream>>>(XW, WPROJ, proj_b, x, n2g, n2b,
                                     WFC1, fc1_b, WFC2, fc2_b, OUT);
}

// Round 16
// 303.464 us; speedup vs baseline: 1.1332x; 1.1332x over previous
//
#include <hip/hip_runtime.h>

#define DEV __device__ __forceinline__

typedef __bf16 bf16x8 __attribute__((ext_vector_type(8)));
typedef float f32x4 __attribute__((ext_vector_type(4)));

DEV float bflo(unsigned int u) { union { unsigned int x; float f; } c; c.x = u << 16; return c.f; }
DEV unsigned short f2bf(float f) {
  union { float f; unsigned int u; } c; c.f = f;
  unsigned int u = c.u;
  return (unsigned short)((u + 0x7fffu + ((u >> 16) & 1u)) >> 16);
}
DEV unsigned int pkbf(float a, float b) {  // {lo=a, hi=b} bf16 pair, RNE
  unsigned int r;
  asm("v_cvt_pk_bf16_f32 %0, %1, %2" : "=v"(r) : "v"(a), "v"(b));
  return r;
}
DEV float gelu_fast(float y) {  // tanh-form GELU via exp2, ~7 VALU ops
  float y2 = y * y;
  float z = y * fmaf(y2, 0.10294348f, 2.30220842f);
  float e = __builtin_amdgcn_exp2f(z);
  float r = __builtin_amdgcn_rcpf(e + 1.0f);
  return fmaf(-y, r, y);
}

DEV void gload16(const void* g, void* l) {
  __builtin_amdgcn_global_load_lds((const __attribute__((address_space(1))) void*)g,
                                   (__attribute__((address_space(3))) void*)l, 16, 0, 0);
}

// ---------------- fused weight convert + zero-pad (dst regions contiguous) --------
__global__ __launch_bounds__(256) void wconv_all(const float* __restrict__ s0,
                                                 const float* __restrict__ s1,
                                                 const float* __restrict__ s2,
                                                 const float* __restrict__ s3,
                                                 unsigned short* __restrict__ dst) {
  int i = blockIdx.x * 256 + threadIdx.x;  // < 516096
  const float* src; int off, real;
  if (i < 122880)      { src = s0; off = i;          real = 110592; }
  else if (i < 172032) { src = s1; off = i - 122880; real = 36864; }
  else if (i < 319488) { src = s2; off = i - 172032; real = 147456; }
  else                 { src = s3; off = i - 319488; real = 147456; }
  dst[i] = (off < real) ? f2bf(src[off]) : (unsigned short)0;
}

// ---------------- bias+mask precompute: BMT4[wth][kk/4][q][kk%4], bf16, log2e ------
__global__ __launch_bounds__(256) void bmt_kernel(const float* __restrict__ rel_table,
                                                  unsigned short* __restrict__ bmt4) {
  int wth = blockIdx.x;            // 0..47 = wt*6 + h
  int wt = wth / 6, h = wth - wt * 6;
  int r = blockIdx.y;              // 0..87 : kk = 4r+i
  unsigned short* row = bmt4 + (((size_t)wth * 88 + r) * 352) * 4;
  for (int q = threadIdx.x; q < 352; q += 256) {
    int mb_q = 0, cls_q = 0;
    bool qv = q < 343;
    if (qv) {
      int ii_q = q / 49, rem_q = q - ii_q * 49;
      int jj_q = rem_q / 7, ww_q = rem_q - jj_q * 7;
      mb_q = ii_q * 169 + jj_q * 13 + ww_q;
      int cd_q = (wt & 4) ? (ii_q < 4 ? 1 : 2) : 0;
      int ch_q = (wt & 2) ? (jj_q < 4 ? 1 : 2) : 0;
      int cw_q = (wt & 1) ? (ww_q < 4 ? 1 : 2) : 0;
      cls_q = cd_q * 9 + ch_q * 3 + cw_q;
    }
    unsigned short ov[4];
#pragma unroll
    for (int i = 0; i < 4; i++) {
      int kk = 4 * r + i;
      float v;
      if (kk >= 343) v = -30000.f;
      else if (!qv) v = 0.f;
      else {
        int ii_k = kk / 49, rem_k = kk - ii_k * 49;
        int jj_k = rem_k / 7, ww_k = rem_k - jj_k * 7;
        int mb_k = ii_k * 169 + jj_k * 13 + ww_k;
        int cd_k = (wt & 4) ? (ii_k < 4 ? 1 : 2) : 0;
        int ch_k = (wt & 2) ? (jj_k < 4 ? 1 : 2) : 0;
        int cw_k = (wt & 1) ? (ww_k < 4 ? 1 : 2) : 0;
        int cls_k = cd_k * 9 + ch_k * 3 + cw_k;
        v = rel_table[(mb_q - mb_k + 1098) * 6 + h] * 1.4426950408889634f;
        if (cls_q != cls_k) v -= 144.26950408889634f;
      }
      ov[i] = f2bf(v);
    }
    unsigned int lo = (unsigned)ov[0] | ((unsigned)ov[1] << 16);
    unsigned int hi = (unsigned)ov[2] | ((unsigned)ov[3] << 16);
    *(uint2*)(row + q * 4) = make_uint2(lo, hi);
  }
}

// ---------------- LayerNorm1 + roll + window gather ----------------
__global__ __launch_bounds__(256) void ln_kernel(const float* __restrict__ x,
                                                 const float* __restrict__ g,
                                                 const float* __restrict__ b,
                                                 unsigned short* __restrict__ out) {
  int row = (blockIdx.x << 2) + (threadIdx.x >> 6);
  int lane = threadIdx.x & 63;
  int w_ = row / 343, n_ = row - w_ * 343;
  int bb = w_ >> 6, wrem = w_ & 63;
  int wd = wrem >> 4, wh = (wrem >> 2) & 3, ww = wrem & 3;
  int ii = n_ / 49, rem = n_ - ii * 49;
  int jj = rem / 7, kk = rem - jj * 7;
  int d = wd * 7 + ii + 3; if (d >= 28) d -= 28;
  int hh = wh * 7 + jj + 3; if (hh >= 28) hh -= 28;
  int wb = ww * 7 + kk + 3; if (wb >= 28) wb -= 28;
  const float* xr = x + ((size_t)bb * 21952 + (d * 28 + hh) * 28 + wb) * 192;
  float v0 = xr[lane], v1 = xr[lane + 64], v2 = xr[lane + 128];
  float s = v0 + v1 + v2;
  float sq = v0 * v0 + v1 * v1 + v2 * v2;
#pragma unroll
  for (int o = 32; o > 0; o >>= 1) {
    s += __shfl_xor(s, o, 64);
    sq += __shfl_xor(sq, o, 64);
  }
  float mean = s * (1.0f / 192.0f);
  float var = sq * (1.0f / 192.0f) - mean * mean;
  float rstd = rsqrtf(var + 1e-5f);
  unsigned short* orow = out + (size_t)row * 192;
  orow[lane]       = f2bf((v0 - mean) * rstd * g[lane] + b[lane]);
  orow[lane + 64]  = f2bf((v1 - mean) * rstd * g[lane + 64] + b[lane + 64]);
  orow[lane + 128] = f2bf((v2 - mean) * rstd * g[lane + 128] + b[lane + 128]);
}

// ---------------- QKV GEMM 128x128, BK=32 (16KB LDS/buf -> 4 blocks/CU) ----------
__global__ __launch_bounds__(256) void gemm_qkv(
    const unsigned short* __restrict__ A, const unsigned short* __restrict__ W,
    const float* __restrict__ bias,
    unsigned short* __restrict__ oq, unsigned short* __restrict__ okk,
    unsigned short* __restrict__ ov) {
  __shared__ __align__(16) unsigned short As[2][128 * 32];
  __shared__ __align__(16) unsigned short Bs[2][128 * 32];
  const int K = 192;
  // bijective XCD swizzle (nwg=3430, q8=428, r8=6)
  const int orig = blockIdx.x;
  const int xcd = orig & 7, off = orig >> 3;
  const int wgid = (xcd < 6 ? xcd * 429 : 2574 + (xcd - 6) * 428) + off;
  const int by = wgid / 5, bx = wgid - by * 5;
  const int bm = by << 7, bn = bx << 7;

  const int tid = threadIdx.x;
  const int lane = tid & 63;
  const int wv = tid >> 6;
  const int wr = wv >> 1, wc = wv & 1;
  const int l15 = lane & 15, l4 = lane >> 4;

  f32x4 acc[4][4];
#pragma unroll
  for (int a = 0; a < 4; a++)
#pragma unroll
    for (int b2 = 0; b2 < 4; b2++) acc[a][b2] = (f32x4){0.f, 0.f, 0.f, 0.f};

  auto stage = [&](int kt, int buf) {  // exactly 4 gload16 per thread
#pragma unroll
    for (int i = 0; i < 2; i++) {
      int o = (i << 12) + (tid << 4);   // byte offset in 8KB tile
      int r = o >> 6;                   // row 0..127
      int c = (o >> 4) & 3;             // 16B chunk 0..3
      int sc = (c ^ (r & 3)) << 3;      // swizzled source col (elems)
      gload16(A + (size_t)(bm + r) * K + kt * 32 + sc, &As[buf][o >> 1]);
      gload16(W + (size_t)(bn + r) * K + kt * 32 + sc, &Bs[buf][o >> 1]);
    }
  };

  stage(0, 0);
  int cur = 0;
  for (int kt = 0; kt < 6; ++kt) {
    if (kt < 5) {
      stage(kt + 1, cur ^ 1);
      asm volatile("s_waitcnt vmcnt(4)" ::: "memory");  // tile kt landed; kt+1 in flight
    } else {
      asm volatile("s_waitcnt vmcnt(0)" ::: "memory");
    }
    __builtin_amdgcn_s_barrier();
    __builtin_amdgcn_sched_barrier(0);
    {
      bf16x8 af[4], bfr[4];
#pragma unroll
      for (int fm = 0; fm < 4; fm++) {
        int r = (wr << 6) + (fm << 4) + l15;
        af[fm] = *(const bf16x8*)(&As[cur][(r << 5) + ((l4 ^ (r & 3)) << 3)]);
      }
#pragma unroll
      for (int fn = 0; fn < 4; fn++) {
        int r = (wc << 6) + (fn << 4) + l15;
        bfr[fn] = *(const bf16x8*)(&Bs[cur][(r << 5) + ((l4 ^ (r & 3)) << 3)]);
      }
#pragma unroll
      for (int fm = 0; fm < 4; fm++)
#pragma unroll
        for (int fn = 0; fn < 4; fn++)
          acc[fm][fn] = __builtin_amdgcn_mfma_f32_16x16x32_bf16(bfr[fn], af[fm], acc[fm][fn], 0, 0, 0);
    }
    if (kt < 5) {
      __builtin_amdgcn_sched_barrier(0);
      __builtin_amdgcn_s_barrier();
      cur ^= 1;
    }
  }

#pragma unroll
  for (int fm = 0; fm < 4; fm++) {
    int gr = bm + (wr << 6) + (fm << 4) + l15;
    int w_ = gr / 343, n_ = gr - w_ * 343;
#pragma unroll
    for (int fn = 0; fn < 4; fn++) {
      int gc0 = bn + (wc << 6) + (fn << 4) + (l4 << 2);
      if (gc0 < 576) {
        float4 bv = *(const float4*)(bias + gc0);
        float v0 = acc[fm][fn][0] + bv.x, v1 = acc[fm][fn][1] + bv.y;
        float v2 = acc[fm][fn][2] + bv.z, v3 = acc[fm][fn][3] + bv.w;
        int which = gc0 / 192;
        int cc3 = gc0 - which * 192;
        int hh2 = cc3 >> 5, dd0 = cc3 & 31;
        size_t offo = ((size_t)(w_ * 6 + hh2) * 343 + n_) * 32 + dd0;
        if (which == 0) {
          const float sc = 0.17677669529663687f * 1.4426950408889634f;
          *(uint2*)(oq + offo) = make_uint2(pkbf(v0 * sc, v1 * sc), pkbf(v2 * sc, v3 * sc));
        } else if (which == 1) {
          *(uint2*)(okk + offo) = make_uint2(pkbf(v0, v1), pkbf(v2, v3));
        } else {
          *(uint2*)(ov + offo) = make_uint2(pkbf(v0, v1), pkbf(v2, v3));
        }
      }
    }
  }
}

// ---------------- fused proj + LN2 + MLP + both residuals, 64 rows/block ----------
// r9 configuration — empirically best of 7 structural variants (150 us).
// launch_bounds(256,2): VGPR cap 256 so weight fragments prefetch into registers.
// Phase 1: proj + x resid -> xnew (regs, bf16), LN2 -> xw2s (LDS, swizzled).
// Phase 2: 6 chunks of 128 hidden: W1-regs -> FC1 -> W2 loads -> GELU -> Hs
// (ping-pong) -> FC2; one barrier per chunk.
__global__ __launch_bounds__(256, 2) void proj_mlp(
    const unsigned short* __restrict__ A,    // attn-out, window order
    const unsigned short* __restrict__ Wp, const float* __restrict__ bp,
    const float* __restrict__ x,
    const float* __restrict__ g2, const float* __restrict__ b2,
    const unsigned short* __restrict__ W1, const float* __restrict__ b1,
    const unsigned short* __restrict__ W2, const float* __restrict__ b2b,
    float* __restrict__ out) {
  __shared__ __align__(16) char smem[59392];
  unsigned short* pBs  = (unsigned short*)smem;            // ph1: Wp slice 192x64 (24K)
  unsigned short* pAs  = (unsigned short*)(smem + 24576);  // ph1: A slice 64x64 (8K)
  unsigned short* xw2s = (unsigned short*)smem;            // ph2: 64x192 (24K)
  unsigned short* Hs0  = (unsigned short*)(smem + 24576);  // ph2: 64x136 (17408B)
  unsigned short* Hs1  = (unsigned short*)(smem + 41984);  // ph2: 64x136 (17408B)
  float* red = (float*)(smem + 24576);                     // LN2 scratch (2K, pre-Hs)

  const int tid = threadIdx.x, lane = tid & 63, wv = tid >> 6;
  const int l15 = lane & 15, l4 = lane >> 4;
  const int bm = blockIdx.x << 6;

  // ---- phase 1: proj GEMM, single-buffered LDS staging ----
  f32x4 acc[4][3];
#pragma unroll
  for (int a = 0; a < 4; a++)
#pragma unroll
    for (int b_ = 0; b_ < 3; b_++) acc[a][b_] = (f32x4){0.f, 0.f, 0.f, 0.f};

  for (int kt = 0; kt < 3; ++kt) {
    __syncthreads();
#pragma unroll
    for (int i = 0; i < 2; i++) {  // A slice 64x64
      int u = (i << 8) + tid;
      int r = u >> 3, ch = u & 7;
      gload16(A + (size_t)(bm + r) * 192 + (kt << 6) + ((ch ^ (r & 7)) << 3), pAs + (u << 3));
    }
#pragma unroll
    for (int i = 0; i < 6; i++) {  // Wp slice 192x64
      int u = (i << 8) + tid;
      int r = u >> 3, ch = u & 7;
      gload16(Wp + (size_t)r * 192 + (kt << 6) + ((ch ^ (r & 7)) << 3), pBs + (u << 3));
    }
    asm volatile("s_waitcnt vmcnt(0)" ::: "memory");
    __syncthreads();
#pragma unroll
    for (int ks = 0; ks < 2; ks++) {
      bf16x8 af[4], bfr[3];
#pragma unroll
      for (int fm = 0; fm < 4; fm++) {
        int r = (fm << 4) + l15;
        int c = (ks << 2) + l4;
        af[fm] = *(const bf16x8*)(pAs + (r << 6) + ((c ^ (r & 7)) << 3));
      }
#pragma unroll
      for (int fn = 0; fn < 3; fn++) {
        int rr = wv * 48 + (fn << 4) + l15;
        int c = (ks << 2) + l4;
        bfr[fn] = *(const bf16x8*)(pBs + (rr << 6) + ((c ^ (rr & 7)) << 3));
      }
#pragma unroll
      for (int fm = 0; fm < 4; fm++)
#pragma unroll
        for (int fn = 0; fn < 3; fn++)
          acc[fm][fn] = __builtin_amdgcn_mfma_f32_16x16x32_bf16(bfr[fn], af[fm], acc[fm][fn], 0, 0, 0);
    }
  }

  // ---- epilogue 1: +bias +x residual (token addressing), LN2 stats ----
  int orow[4];
#pragma unroll
  for (int fm = 0; fm < 4; fm++) {
    int gr = bm + (fm << 4) + l15;
    int w_ = gr / 343, n_ = gr - w_ * 343;
    int bb = w_ >> 6, wrem = w_ & 63;
    int wd = wrem >> 4, wh = (wrem >> 2) & 3, ww = wrem & 3;
    int ii = n_ / 49, rem = n_ - ii * 49;
    int jj = rem / 7, kk = rem - jj * 7;
    int d = wd * 7 + ii + 3; if (d >= 28) d -= 28;
    int hh = wh * 7 + jj + 3; if (hh >= 28) hh -= 28;
    int wb = ww * 7 + kk + 3; if (wb >= 28) wb -= 28;
    orow[fm] = ((bb * 21952 + (d * 28 + hh) * 28 + wb) * 192);
  }
  float ps[4], psq[4];
#pragma unroll
  for (int fm = 0; fm < 4; fm++) {
    float s = 0.f, sq = 0.f;
#pragma unroll
    for (int fn = 0; fn < 3; fn++) {
      int gc0 = wv * 48 + (fn << 4) + (l4 << 2);
      float4 bv = *(const float4*)(bp + gc0);
      float4 xv = *(const float4*)(x + (size_t)orow[fm] + gc0);
      acc[fm][fn][0] += bv.x + xv.x;
      acc[fm][fn][1] += bv.y + xv.y;
      acc[fm][fn][2] += bv.z + xv.z;
      acc[fm][fn][3] += bv.w + xv.w;
#pragma unroll
      for (int i = 0; i < 4; i++) {
        float v = acc[fm][fn][i];
        s += v; sq += v * v;
      }
    }
    ps[fm] = s; psq[fm] = sq;
  }
#pragma unroll
  for (int fm = 0; fm < 4; fm++) {
    ps[fm] += __shfl_xor(ps[fm], 16, 64);
    ps[fm] += __shfl_xor(ps[fm], 32, 64);
    psq[fm] += __shfl_xor(psq[fm], 16, 64);
    psq[fm] += __shfl_xor(psq[fm], 32, 64);
  }
  __syncthreads();  // all proj LDS reads done; pBs/pAs areas reusable
  if (l4 == 0) {
#pragma unroll
    for (int fm = 0; fm < 4; fm++) {
      int tr = (fm << 4) + l15;
      red[tr * 8 + wv] = ps[fm];
      red[tr * 8 + 4 + wv] = psq[fm];
    }
  }
  __syncthreads();
  if (tid < 64) {
    float s = red[tid * 8] + red[tid * 8 + 1] + red[tid * 8 + 2] + red[tid * 8 + 3];
    float sq = red[tid * 8 + 4] + red[tid * 8 + 5] + red[tid * 8 + 6] + red[tid * 8 + 7];
    float mean = s * (1.0f / 192.0f);
    float var = sq * (1.0f / 192.0f) - mean * mean;
    red[tid * 8] = mean;
    red[tid * 8 + 1] = rsqrtf(var + 1e-5f);
  }
  __syncthreads();
  // xnew -> packed bf16 regs; xw2 = LN2(xnew) -> LDS (swizzled for phase-2 reads)
  unsigned int xnb[4][3][2];
#pragma unroll
  for (int fm = 0; fm < 4; fm++) {
    int tr = (fm << 4) + l15;
    float mean = red[tr * 8], rstd = red[tr * 8 + 1];
#pragma unroll
    for (int fn = 0; fn < 3; fn++) {
      int gc0 = wv * 48 + (fn << 4) + (l4 << 2);
      float4 gv = *(const float4*)(g2 + gc0);
      float4 b2v = *(const float4*)(b2 + gc0);
      float v0 = acc[fm][fn][0], v1 = acc[fm][fn][1];
      float v2 = acc[fm][fn][2], v3 = acc[fm][fn][3];
      xnb[fm][fn][0] = pkbf(v0, v1);
      xnb[fm][fn][1] = pkbf(v2, v3);
      float y0 = (v0 - mean) * rstd * gv.x + b2v.x;
      float y1 = (v1 - mean) * rstd * gv.y + b2v.y;
      float y2 = (v2 - mean) * rstd * gv.z + b2v.z;
      float y3 = (v3 - mean) * rstd * gv.w + b2v.w;
      int ch = gc0 >> 3;
      *(uint2*)(xw2s + tr * 192 + ((ch ^ (tr & 7)) << 3) + (gc0 & 7)) =
          make_uint2(pkbf(y0, y1), pkbf(y2, y3));
    }
  }
  __syncthreads();

  // ---- phase 2: MLP over 6 chunks of 128 hidden cols, reg-prefetched weights ----
  f32x4 acc2[4][3];
#pragma unroll
  for (int a = 0; a < 4; a++)
#pragma unroll
    for (int b_ = 0; b_ < 3; b_++) acc2[a][b_] = (f32x4){0.f, 0.f, 0.f, 0.f};

#pragma unroll
  for (int cc = 0; cc < 6; cc++) {
    unsigned short* Hc = (cc & 1) ? Hs1 : Hs0;
    // prefetch all W1 frags for this chunk (12 x bf16x8 = 48 VGPR)
    bf16x8 w1r[2][6];
#pragma unroll
    for (int fn = 0; fn < 2; fn++)
#pragma unroll
      for (int ks = 0; ks < 6; ks++) {
        int hrow = (cc << 7) + (wv << 5) + (fn << 4) + l15;
        w1r[fn][ks] = *(const bf16x8*)(W1 + (size_t)hrow * 192 + (ks << 5) + (l4 << 3));
      }
    // FC1
    f32x4 acc1[4][2];
#pragma unroll
    for (int a = 0; a < 4; a++) {
      acc1[a][0] = (f32x4){0.f, 0.f, 0.f, 0.f};
      acc1[a][1] = (f32x4){0.f, 0.f, 0.f, 0.f};
    }
#pragma unroll
    for (int ks = 0; ks < 6; ks++) {
      bf16x8 af[4];
#pragma unroll
      for (int fm = 0; fm < 4; fm++) {
        int r = (fm << 4) + l15;
        int ch = (ks << 2) + l4;
        af[fm] = *(const bf16x8*)(xw2s + r * 192 + ((ch ^ (r & 7)) << 3));
      }
#pragma unroll
      for (int fm = 0; fm < 4; fm++)
#pragma unroll
        for (int fn = 0; fn < 2; fn++)
          acc1[fm][fn] = __builtin_amdgcn_mfma_f32_16x16x32_bf16(w1r[fn][ks], af[fm], acc1[fm][fn], 0, 0, 0);
    }
    // prefetch W2 frags for this chunk (12 x bf16x8); latency hides under GELU
    bf16x8 w2r[3][4];
#pragma unroll
    for (int fn = 0; fn < 3; fn++)
#pragma unroll
      for (int ks = 0; ks < 4; ks++) {
        int j = wv * 48 + (fn << 4) + l15;
        w2r[fn][ks] = *(const bf16x8*)(W2 + (size_t)j * 768 + (cc << 7) + (ks << 5) + (l4 << 3));
      }
    // GELU -> Hc (ping-pong buffer; barrier only between write and read)
#pragma unroll
    for (int fm = 0; fm < 4; fm++) {
      int r = (fm << 4) + l15;
#pragma unroll
      for (int fn = 0; fn < 2; fn++) {
        int hc = (wv << 5) + (fn << 4) + (l4 << 2);
        float4 bv = *(const float4*)(b1 + (cc << 7) + hc);
        float g0 = gelu_fast(acc1[fm][fn][0] + bv.x);
        float g1 = gelu_fast(acc1[fm][fn][1] + bv.y);
        float g2_ = gelu_fast(acc1[fm][fn][2] + bv.z);
        float g3 = gelu_fast(acc1[fm][fn][3] + bv.w);
        *(uint2*)(Hc + r * 136 + hc) = make_uint2(pkbf(g0, g1), pkbf(g2_, g3));
      }
    }
    __syncthreads();
    // FC2 accumulate
#pragma unroll
    for (int ks = 0; ks < 4; ks++) {
      bf16x8 hf[4];
#pragma unroll
      for (int fm = 0; fm < 4; fm++) {
        int r = (fm << 4) + l15;
        hf[fm] = *(const bf16x8*)(Hc + r * 136 + (ks << 5) + (l4 << 3));
      }
#pragma unroll
      for (int fm = 0; fm < 4; fm++)
#pragma unroll
        for (int fn = 0; fn < 3; fn++)
          acc2[fm][fn] = __builtin_amdgcn_mfma_f32_16x16x32_bf16(w2r[fn][ks], hf[fm], acc2[fm][fn], 0, 0, 0);
    }
  }

  // ---- final epilogue: + b2 + xnew -> f32 out (token order), float4 stores ----
#pragma unroll
  for (int fm = 0; fm < 4; fm++) {
#pragma unroll
    for (int fn = 0; fn < 3; fn++) {
      int gc0 = wv * 48 + (fn << 4) + (l4 << 2);
      float4 bv = *(const float4*)(b2b + gc0);
      float4 o;
      o.x = acc2[fm][fn][0] + bv.x + bflo(xnb[fm][fn][0] & 0xffffu);
      o.y = acc2[fm][fn][1] + bv.y + bflo(xnb[fm][fn][0] >> 16);
      o.z = acc2[fm][fn][2] + bv.z + bflo(xnb[fm][fn][1] & 0xffffu);
      o.w = acc2[fm][fn][3] + bv.w + bflo(xnb[fm][fn][1] >> 16);
      *(float4*)(out + (size_t)orow[fm] + gc0) = o;
    }
  }
}

// ---------------- MFMA attention: LDS K/V^T, grouped grid, packed bias ----------
__global__ __launch_bounds__(256) void attn_mfma(const unsigned short* __restrict__ q,
                                                 const unsigned short* __restrict__ k,
                                                 const unsigned short* __restrict__ v,
                                                 const unsigned short* __restrict__ bmt4,
                                                 unsigned short* __restrict__ out) {
  __shared__ __align__(16) unsigned short Ks[352 * 32];
  __shared__ __align__(16) unsigned short Vt[32 * 360];

  // decode blockIdx: h slow, then window-class groups (BMT slab L2 locality)
  const int blk = blockIdx.x;
  const int h_ = blk >> 8;
  const int idx = blk & 255;
  const int cums[8] = {0, 108, 144, 180, 192, 228, 240, 252};
  int c = (idx >= 108) + (idx >= 144) + (idx >= 180) + (idx >= 192) +
          (idx >= 228) + (idx >= 240) + (idx >= 252);
  int r0 = idx - cums[c];
  int sh = (c & 2) ? 1 : 3, sw = (c & 1) ? 1 : 3;
  int p = ((c & 4) ? 1 : 3) * sh * sw;
  int b = r0 / p, q2 = r0 - b * p;
  int wd, wh, ww;
  if (c & 4) wd = 3; else { wd = q2 / (sh * sw); q2 -= wd * sh * sw; }
  if (c & 2) wh = 3; else { wh = q2 / sw; q2 -= wh * sw; }
  ww = (c & 1) ? 3 : q2;
  const int w_ = b * 64 + wd * 16 + wh * 4 + ww;
  const int wt = c;
  const int blkqkv = w_ * 6 + h_;

  const int t = threadIdx.x, lane = t & 63, wv = t >> 6;
  const int l15 = lane & 15, l4 = lane >> 4;
  const unsigned short* Qb = q + (size_t)blkqkv * (343 * 32);
  const unsigned short* Kb = k + (size_t)blkqkv * (343 * 32);
  const unsigned short* Vb = v + (size_t)blkqkv * (343 * 32);
  const unsigned short* bm4 = bmt4 + ((size_t)(wt * 6 + h_) * 88) * 352 * 4;

  // stage K (rows 343..351 zeroed), chunk-XOR swizzle for 2-way reads
  for (int cc = t; cc < 1408; cc += 256) {
    int r = cc >> 2, ch = cc & 3;
    int swc = ch ^ ((r >> 1) & 3);
    uint4 val = make_uint4(0, 0, 0, 0);
    if (r < 343) val = *(const uint4*)(Kb + r * 32 + ch * 8);
    *(uint4*)(Ks + r * 32 + swc * 8) = val;
  }
  // stage V^T: Vt[d][n] = V[n][d]; pad n in [343,352) zeroed
#pragma unroll
  for (int ch = 0; ch < 4; ch++) {
    for (int n = t; n < 343; n += 256) {
      union { uint4 u4; unsigned short us[8]; } val;
      val.u4 = *(const uint4*)(Vb + n * 32 + ch * 8);
#pragma unroll
      for (int j = 0; j < 8; j++) Vt[(ch * 8 + j) * 360 + n] = val.us[j];
    }
  }
  for (int cc = t; cc < 288; cc += 256) {
    int d = cc / 9, n = 343 + (cc - d * 9);
    Vt[d * 360 + n] = 0;
  }
  __syncthreads();

  const int ksw = (l4 ^ ((l15 >> 1) & 3)) << 3;

  for (int tq = wv; tq < 22; tq += 4) {
    int qrow = tq * 16 + l15; if (qrow > 342) qrow = 342;
    bf16x8 qf = *(const bf16x8*)(Qb + qrow * 32 + l4 * 8);

    unsigned int u0[22], u1[22];
    float lsum = 0.f;
    __builtin_amdgcn_s_setprio(1);
#pragma unroll
    for (int kt = 0; kt < 22; kt++) {
      bf16x8 kf = *(const bf16x8*)(Ks + (kt * 16 + l15) * 32 + ksw);
      f32x4 s = __builtin_amdgcn_mfma_f32_16x16x32_bf16(kf, qf, (f32x4){0.f, 0.f, 0.f, 0.f}, 0, 0, 0);
      const unsigned short* bp = bm4 + ((size_t)((kt << 2) + l4) * 352 + (tq << 4) + l15) * 4;
      uint2 bv = *(const uint2*)bp;
      float p0 = __builtin_amdgcn_exp2f(s[0] + bflo(bv.x & 0xffffu));
      float p1 = __builtin_amdgcn_exp2f(s[1] + bflo(bv.x >> 16));
      float p2 = __builtin_amdgcn_exp2f(s[2] + bflo(bv.y & 0xffffu));
      float p3 = __builtin_amdgcn_exp2f(s[3] + bflo(bv.y >> 16));
      lsum += (p0 + p1) + (p2 + p3);
      asm("v_cvt_pk_bf16_f32 %0, %1, %2" : "=v"(u0[kt]) : "v"(p0), "v"(p1));
      asm("v_cvt_pk_bf16_f32 %0, %1, %2" : "=v"(u1[kt]) : "v"(p2), "v"(p3));
    }
    __builtin_amdgcn_s_setprio(0);
    lsum += __shfl_xor(lsum, 16, 64);
    lsum += __shfl_xor(lsum, 32, 64);
    float inv = 1.0f / lsum;  // per-lane q = l15

    // O^T = mfma(V^T, P): lane holds O[q = l15][d = 4*l4 .. +3] (+16 for oacc1)
    f32x4 oacc0 = (f32x4){0.f, 0.f, 0.f, 0.f};
    f32x4 oacc1 = (f32x4){0.f, 0.f, 0.f, 0.f};
    __builtin_amdgcn_s_setprio(1);
#pragma unroll
    for (int ck = 0; ck < 11; ck++) {
      unsigned int dw[4];
#pragma unroll
      for (int d = 0; d < 4; d++) {
        int src = l15 + 16 * ((d >> 1) + 2 * (l4 & 1));
        unsigned int x = __shfl((d & 1) ? u1[2 * ck] : u0[2 * ck], src, 64);
        unsigned int y = __shfl((d & 1) ? u1[2 * ck + 1] : u0[2 * ck + 1], src, 64);
        dw[d] = (l4 < 2) ? x : y;
      }
      union { unsigned int u[4]; bf16x8 v; } pc;
      pc.u[0] = dw[0]; pc.u[1] = dw[1]; pc.u[2] = dw[2]; pc.u[3] = dw[3];
      bf16x8 vf0 = *(const bf16x8*)(Vt + (size_t)l15 * 360 + ck * 32 + l4 * 8);
      bf16x8 vf1 = *(const bf16x8*)(Vt + (size_t)(16 + l15) * 360 + ck * 32 + l4 * 8);
      oacc0 = __builtin_amdgcn_mfma_f32_16x16x32_bf16(vf0, pc.v, oacc0, 0, 0, 0);
      oacc1 = __builtin_amdgcn_mfma_f32_16x16x32_bf16(vf1, pc.v, oacc1, 0, 0, 0);
    }
    __builtin_amdgcn_s_setprio(0);

    int qg = tq * 16 + l15;
    if (qg < 343) {
      unsigned short* orow = out + ((size_t)w_ * 343 + qg) * 192 + h_ * 32;
      *(uint2*)(orow + (l4 << 2)) =
          make_uint2(pkbf(oacc0[0] * inv, oacc0[1] * inv), pkbf(oacc0[2] * inv, oacc0[3] * inv));
      *(uint2*)(orow + 16 + (l4 << 2)) =
          make_uint2(pkbf(oacc1[0] * inv, oacc1[1] * inv), pkbf(oacc1[2] * inv, oacc1[3] * inv));
    }
  }
}

// ---------------- launcher ----------------
extern "C" void kernel_launch(void* const* d_in, const int* in_sizes, int n_in,
                              void* d_out, int out_size, void* d_ws, size_t ws_size,
                              hipStream_t stream) {
  const float* x      = (const float*)d_in[0];
  const float* n1g    = (const float*)d_in[1];
  const float* n1b    = (const float*)d_in[2];
  const float* qkv_w  = (const float*)d_in[3];
  const float* qkv_b  = (const float*)d_in[4];
  const float* proj_w = (const float*)d_in[5];
  const float* proj_b = (const float*)d_in[6];
  const float* rel_t  = (const float*)d_in[7];
  const float* n2g    = (const float*)d_in[8];
  const float* n2b    = (const float*)d_in[9];
  const float* fc1_w  = (const float*)d_in[10];
  const float* fc1_b  = (const float*)d_in[11];
  const float* fc2_w  = (const float*)d_in[12];
  const float* fc2_b  = (const float*)d_in[13];

  char* ws = (char*)d_ws;
  // layout (bytes):
  // 0         W (QKV|PROJ|FC1|FC2)   1032192
  // 1032192   XW    87808x192 bf16   (33718272)   [ln1-out -> attn-out]
  // 34750464  Q_    1536x343x32 bf16 (33718272)
  // 68468736  K_    1536x343x32 bf16 (33718272)
  // 102187008 V_    1536x343x32 bf16 (33718272)
  // 135925248 BMT4  48x88x352x4 bf16 (11894784)
  if (ws_size < 147820032ull) return;
  unsigned short* WQKV  = (unsigned short*)(ws);
  unsigned short* WPROJ = (unsigned short*)(ws + 245760);
  unsigned short* WFC1  = (unsigned short*)(ws + 344064);
  unsigned short* WFC2  = (unsigned short*)(ws + 638976);
  unsigned short* XW    = (unsigned short*)(ws + 1032192);
  unsigned short* Q_    = (unsigned short*)(ws + 34750464);
  unsigned short* K_    = (unsigned short*)(ws + 68468736);
  unsigned short* V_    = (unsigned short*)(ws + 102187008);
  unsigned short* BMT4  = (unsigned short*)(ws + 135925248);
  float* OUT = (float*)d_out;

  wconv_all<<<2016, 256, 0, stream>>>(qkv_w, proj_w, fc1_w, fc2_w, WQKV);

  bmt_kernel<<<dim3(48, 88), 256, 0, stream>>>(rel_t, BMT4);

  ln_kernel<<<21952, 256, 0, stream>>>(x, n1g, n1b, XW);

  gemm_qkv<<<3430, 256, 0, stream>>>(XW, WQKV, qkv_b, Q_, K_, V_);

  attn_mfma<<<1536, 256, 0, stream>>>(Q_, K_, V_, BMT4, XW);

  proj_mlp<<<1372, 256, 0, stream>>>(XW, WPROJ, proj_b, x, n2g, n2b,
                                     WFC1, fc1_b, WFC2, fc2_b, OUT);
}